// Round 6
// baseline (343.070 us; speedup 1.0000x reference)
//
#include <hip/hip_runtime.h>
#include <hip/hip_bf16.h>

typedef __bf16 bf16_t;
typedef bf16_t bf16x8 __attribute__((ext_vector_type(8)));
typedef float  f32x4  __attribute__((ext_vector_type(4)));

#define B_    16
#define S_    2048
#define H_    768
#define E_    32
#define M_    4
#define P_    128
#define L_    97
#define NPAIR 2048
#define RSPLIT 48

// workspace layout (bytes)
#define OFF_WHT  0u
#define OFF_WTT  (OFF_WHT + 768u*768u*2u)
#define OFF_WCG  (OFF_WTT + 768u*768u*2u)          // 768 chunks x (112 l x 64 j) halfs, XOR-swizzled
#define OFF_ENT  (OFF_WCG + 768u*14336u)
#define OFF_ZS   (OFF_ENT + 512u*768u*2u)
#define OFF_ZO   (OFF_ZS  + 512u*768u*2u)
#define OFF_PART (OFF_ZO  + 512u*768u*2u)          // 48 x 112 x 2048 bf16 split-K partials [c][l][n]

typedef __attribute__((address_space(1))) const unsigned gu32;
typedef __attribute__((address_space(3))) unsigned lu32;

static __device__ __forceinline__ float bf_lo(unsigned u) { return __builtin_bit_cast(float, u << 16); }
static __device__ __forceinline__ float bf_hi(unsigned u) { return __builtin_bit_cast(float, u & 0xffff0000u); }
static __device__ __forceinline__ unsigned short bf_bits(float f) {
    return __builtin_bit_cast(unsigned short, (bf16_t)f);
}

// ---------------- k_prep: fused transpose(Wh,Wt) + build WcG + entity sum ----------------
// blocks [0,1152): transpose; [1152,1920): wcg; [1920,2432): ent.
__global__ __launch_bounds__(256) void k_prep(const float* __restrict__ Wh,
                                              const float* __restrict__ Wt,
                                              const float* __restrict__ Wc,
                                              const float* __restrict__ tf,
                                              const int* __restrict__ pos,
                                              bf16_t* __restrict__ whT,
                                              bf16_t* __restrict__ wtT,
                                              unsigned* __restrict__ wcg,
                                              bf16_t* __restrict__ ent) {
    int bid = blockIdx.x;
    if (bid < 1152) {
        // ---- transpose Wh/Wt (768x768 f32) -> bf16 col-major ----
        __shared__ float tile[32][33];
        int z   = bid / 576;
        int rem = bid - z * 576;
        const float* W = z ? Wt : Wh;
        bf16_t* WT = z ? wtT : whT;
        int k0 = (rem % 24) * 32, c0 = (rem / 24) * 32;
        int tx = threadIdx.x & 31, ty = threadIdx.x >> 5;  // 32 x 8
        for (int r = 0; r < 4; r++) {
            int ky = ty + r * 8;
            tile[ky][tx] = W[(k0 + ky) * H_ + c0 + tx];
        }
        __syncthreads();
        for (int r = 0; r < 4; r++) {
            int cy = ty + r * 8;
            WT[(c0 + cy) * H_ + (k0 + tx)] = (bf16_t)tile[tx][cy];
        }
    } else if (bid < 1920) {
        // ---- build WcG bf16, chunk-major, XOR-swizzled within rows ----
        // Row l's 8 dword-groups stored at physical group g' = g ^ (l&7) so identity
        // global->LDS staging yields conflict-free b128 fragment reads in k_bilinear.
        int I = bid - 1152;                      // 0..767
        unsigned base_dw = (unsigned)I * 3584u;  // dwords per chunk = 112*32
        for (int r = 0; r < 14; r++) {
            int d  = threadIdx.x + 256 * r;      // dest dword in chunk 0..3583
            int l  = d >> 5;                     // 0..111
            int gp = (d >> 2) & 7;               // physical group
            int k  = d & 3;
            int gl = gp ^ (l & 7);               // logical group
            int j  = (gl * 4 + k) * 2;           // logical half index (even)
            int p  = I * 64 + j;                 // = kblk*4096 + i*64 + j
            float v0 = (l < L_) ? Wc[(size_t)p * L_ + l]       : 0.f;
            float v1 = (l < L_) ? Wc[(size_t)(p + 1) * L_ + l] : 0.f;
            unsigned pk = (unsigned)bf_bits(v0) | ((unsigned)bf_bits(v1) << 16);
            wcg[base_dw + d] = pk;
        }
    } else {
        // ---- entity features (dedup-weighted mention sum) -> bf16 ----
        int be = bid - 1920;    // b*32+e, 0..511
        int b  = be >> 5;
        int p0 = pos[be*4+0], p1 = pos[be*4+1], p2 = pos[be*4+2], p3 = pos[be*4+3];
        bool w1 = (p1 != p0);
        bool w2 = (p2 != p0) && (p2 != p1);
        bool w3 = (p3 != p0) && (p3 != p1) && (p3 != p2);
        const float* base = tf + (size_t)b * S_ * H_;
        for (int qq = 0; qq < 3; qq++) {
            int h = threadIdx.x + qq * 256;
            float s = base[(size_t)p0 * H_ + h];
            if (w1) s += base[(size_t)p1 * H_ + h];
            if (w2) s += base[(size_t)p2 * H_ + h];
            if (w3) s += base[(size_t)p3 * H_ + h];
            ent[(size_t)be * H_ + h] = (bf16_t)s;
        }
    }
}

// ---------------- K2: z_ent = tanh(ent @ W + b) via MFMA, per-entity (512 rows) ----------------
__global__ __launch_bounds__(256) void k_gemm_z(const bf16_t* __restrict__ ent,
                                                const bf16_t* __restrict__ whT,
                                                const bf16_t* __restrict__ wtT,
                                                const float* __restrict__ bh,
                                                const float* __restrict__ bt,
                                                bf16_t* __restrict__ zs,
                                                bf16_t* __restrict__ zo) {
    const bf16_t* WT  = blockIdx.z ? wtT : whT;
    const float* bias = blockIdx.z ? bt  : bh;
    bf16_t* outp      = blockIdx.z ? zo  : zs;
    int w = threadIdx.x >> 6, lane = threadIdx.x & 63;
    int ml = lane & 15, q = lane >> 4;
    int m0 = blockIdx.x * 64 + w * 16;   // entity row tile
    int c0 = blockIdx.y * 64;            // col tile base
    f32x4 zero4 = {0.f, 0.f, 0.f, 0.f};
    f32x4 acc[4] = {zero4, zero4, zero4, zero4};
    const bf16_t* aptr = ent + (size_t)(m0 + ml) * H_ + q * 8;
    for (int kk = 0; kk < 24; kk++) {
        bf16x8 a = *reinterpret_cast<const bf16x8*>(aptr + kk * 32);
        for (int lt = 0; lt < 4; lt++) {
            const bf16_t* bp = WT + (size_t)(c0 + lt * 16 + ml) * H_ + kk * 32 + q * 8;
            bf16x8 bfr = *reinterpret_cast<const bf16x8*>(bp);
            acc[lt] = __builtin_amdgcn_mfma_f32_16x16x32_bf16(a, bfr, acc[lt], 0, 0, 0);
        }
    }
    for (int lt = 0; lt < 4; lt++)
        for (int r = 0; r < 4; r++) {
            int row = q * 4 + r;
            int col = c0 + lt * 16 + ml;
            float v = tanhf(acc[lt][r] + bias[col]);
            outp[(size_t)(m0 + row) * H_ + col] = (bf16_t)v;
        }
}

// ---------------- K3: bilinear classifier, split-K, 4 waves x 4 n-tiles, dbuf async staging --
// logits[n,l] += zs[n,i] * ( sum_j zo[n,j] * Wc[kblk,i,j,l] ), inner sum via MFMA K=64.
// ht[] entity indices are BATCH-LOCAL (0..31); global entity = (n>>7)*32 + ht.
// LDS-BW-bound: every wave reads the full 14KB Wc slice per ii, so traffic ~ wave count.
// 4 waves x 4 n-tiles maximizes B-fragment reuse (4 n-tiles share each ds_read_b128).
// launch_bounds(256,3): VGPR<=170 -> 3 blocks/CU (LDS 36.9KB allows 4); the 16 per-iter
// barrier drains need >8 waves/CU to hide (m114: wave-level overlap is the mechanism).
__global__ __launch_bounds__(256, 3) void k_bilinear(const bf16_t* __restrict__ zs,
                                                     const bf16_t* __restrict__ zo,
                                                     const unsigned* __restrict__ wcg,
                                                     const int* __restrict__ ht,
                                                     unsigned* __restrict__ pout) {
    __shared__ __align__(16) unsigned wc_lds[2][112 * 32];  // dbuf, 14336 B each, swizzled
    __shared__ unsigned short zs_lds[16 * 256];             // [i][pair-in-block]
    int nb = blockIdx.x;           // 0..7  (256 pairs each)
    int c  = blockIdx.y;           // 0..47 (16 I's each)
    int I0 = c * 16;
    int kblk = I0 >> 6;
    int i0   = I0 & 63;
    int t = threadIdx.x;
    int w = t >> 6, lane = t & 63, ml = lane & 15, q = lane >> 4;
    int nbase = nb * 256;

    // stage zs transposed: zs_lds[ii][p] = zs_ent[global_ent(ht[n,0])][kblk*64 + i0 + ii]
    {
        int n  = nbase + t;
        int es = (n >> 7) * E_ + ht[n * 2 + 0];
        const unsigned short* src =
            reinterpret_cast<const unsigned short*>(zs) + (size_t)es * H_ + kblk * 64 + i0;
        uint4 u0 = *reinterpret_cast<const uint4*>(src);
        uint4 u1 = *reinterpret_cast<const uint4*>(src + 8);
        unsigned vals[8] = {u0.x, u0.y, u0.z, u0.w, u1.x, u1.y, u1.z, u1.w};
        for (int d = 0; d < 8; d++) {
            zs_lds[(2 * d) * 256 + t]     = (unsigned short)(vals[d] & 0xffffu);
            zs_lds[(2 * d + 1) * 256 + t] = (unsigned short)(vals[d] >> 16);
        }
    }

    // zo A-operand fragments: wave w owns n-tiles (w*4+nt)
    bf16x8 zoA[4][2];
    for (int nt = 0; nt < 4; nt++) {
        int n  = nbase + (w * 4 + nt) * 16 + ml;
        int eo = (n >> 7) * E_ + ht[n * 2 + 1];
        const bf16_t* src = zo + (size_t)eo * H_ + kblk * 64;
        zoA[nt][0] = *reinterpret_cast<const bf16x8*>(src + 0 * 32 + q * 8);
        zoA[nt][1] = *reinterpret_cast<const bf16x8*>(src + 1 * 32 + q * 8);
    }

    f32x4 zero4 = {0.f, 0.f, 0.f, 0.f};
    f32x4 acc[4][7];
    for (int nt = 0; nt < 4; nt++)
        for (int lt = 0; lt < 7; lt++) acc[nt][lt] = zero4;

    const unsigned* gsrc = wcg + (size_t)I0 * 3584u;

    // async prefetch chunk 0 into buf 0 (identity copy; swizzle pre-baked in wcg)
    for (int pp = w; pp < 14; pp += 4)
        __builtin_amdgcn_global_load_lds((gu32*)(gsrc + pp * 256 + lane * 4),
                                         (lu32*)&wc_lds[0][pp * 256], 16, 0, 0);
    __syncthreads();  // zs_lds ready + prefetch(0) drained

    int sw = ml & 7;  // l&7 == ml&7 for l = lt*16+ml
    for (int ii = 0; ii < 16; ii++) {
        int pb = ii & 1;
        // issue prefetch of chunk ii+1 BEFORE compute so latency hides behind MFMA
        if (ii < 15) {
            const unsigned* g2 = gsrc + (size_t)(ii + 1) * 3584u;
            for (int pp = w; pp < 14; pp += 4)
                __builtin_amdgcn_global_load_lds((gu32*)(g2 + pp * 256 + lane * 4),
                                                 (lu32*)&wc_lds[1 - pb][pp * 256], 16, 0, 0);
        }

        // zs scalars for this i: rows q*4+r of each n-tile
        float zsv[4][4];
        for (int nt = 0; nt < 4; nt++) {
            const unsigned* zp = reinterpret_cast<const unsigned*>(
                &zs_lds[ii * 256 + (w * 4 + nt) * 16 + q * 4]);
            unsigned z0 = zp[0], z1 = zp[1];
            zsv[nt][0] = bf_lo(z0); zsv[nt][1] = bf_hi(z0);
            zsv[nt][2] = bf_lo(z1); zsv[nt][3] = bf_hi(z1);
        }

        const unsigned short* wch = reinterpret_cast<const unsigned short*>(wc_lds[pb]);
        for (int lt = 0; lt < 7; lt++) {
            int l = lt * 16 + ml;
            bf16x8 b0 = *reinterpret_cast<const bf16x8*>(wch + l * 64 + ((q ^ sw) * 8));
            bf16x8 b1 = *reinterpret_cast<const bf16x8*>(wch + l * 64 + (((4 + q) ^ sw) * 8));
            for (int nt = 0; nt < 4; nt++) {
                f32x4 dres = __builtin_amdgcn_mfma_f32_16x16x32_bf16(zoA[nt][0], b0, zero4, 0, 0, 0);
                dres = __builtin_amdgcn_mfma_f32_16x16x32_bf16(zoA[nt][1], b1, dres, 0, 0, 0);
                for (int r = 0; r < 4; r++) acc[nt][lt][r] += zsv[nt][r] * dres[r];
            }
        }
        __syncthreads();  // drains prefetch(ii+1); all waves done with buf pb
    }

    // epilogue: bf16 partials, layout part[c][l][n] — lane's 4 values are consecutive n
    // for one l, so pack into one 8B store.
    for (int nt = 0; nt < 4; nt++) {
        int n0 = nbase + (w * 4 + nt) * 16 + q * 4;
        for (int lt = 0; lt < 7; lt++) {
            int l = lt * 16 + ml;
            unsigned d0 = (unsigned)bf_bits(acc[nt][lt][0]) | ((unsigned)bf_bits(acc[nt][lt][1]) << 16);
            unsigned d1 = (unsigned)bf_bits(acc[nt][lt][2]) | ((unsigned)bf_bits(acc[nt][lt][3]) << 16);
            uint2 pk = {d0, d1};
            *reinterpret_cast<uint2*>(pout + (((size_t)c * 112 + l) * NPAIR + n0) / 2) = pk;
        }
    }
}

// ---------------- K4: split-K reduction + bias (bf16 partials, [c][l][n]) ----------------
__global__ __launch_bounds__(256) void k_reduce(const unsigned* __restrict__ part,
                                                const float* __restrict__ bc,
                                                float* __restrict__ out) {
    int t = blockIdx.x * 256 + threadIdx.x;   // over 97 * 512
    if (t >= L_ * (NPAIR / 4)) return;
    int n4 = t & 511;            // n/4
    int l  = t >> 9;             // 0..96
    const unsigned* p = part + (size_t)l * (NPAIR / 2) + n4 * 2;
    f32x4 s = {0.f, 0.f, 0.f, 0.f};
    #pragma unroll
    for (int cc = 0; cc < RSPLIT; cc++) {
        uint2 v = *reinterpret_cast<const uint2*>(p + (size_t)cc * 112 * (NPAIR / 2));
        s[0] += bf_lo(v.x); s[1] += bf_hi(v.x);
        s[2] += bf_lo(v.y); s[3] += bf_hi(v.y);
    }
    float b = bc[l];
    #pragma unroll
    for (int e = 0; e < 4; e++)
        out[(size_t)(n4 * 4 + e) * L_ + l] = s[e] + b;
}

extern "C" void kernel_launch(void* const* d_in, const int* in_sizes, int n_in,
                              void* d_out, int out_size, void* d_ws, size_t ws_size,
                              hipStream_t stream) {
    (void)in_sizes; (void)n_in; (void)out_size; (void)ws_size;
    const float* tf  = (const float*)d_in[0];
    const int*   pos = (const int*)d_in[1];
    const int*   ht  = (const int*)d_in[2];
    const float* Wh  = (const float*)d_in[3];
    const float* bh  = (const float*)d_in[4];
    const float* Wt  = (const float*)d_in[5];
    const float* bt  = (const float*)d_in[6];
    const float* Wc  = (const float*)d_in[7];
    const float* bc  = (const float*)d_in[8];
    float* out = (float*)d_out;
    char*  ws  = (char*)d_ws;

    bf16_t*   whT  = (bf16_t*)(ws + OFF_WHT);
    bf16_t*   wtT  = (bf16_t*)(ws + OFF_WTT);
    unsigned* wcg  = (unsigned*)(ws + OFF_WCG);
    bf16_t*   ent  = (bf16_t*)(ws + OFF_ENT);
    bf16_t*   zsp  = (bf16_t*)(ws + OFF_ZS);
    bf16_t*   zop  = (bf16_t*)(ws + OFF_ZO);
    unsigned* part = (unsigned*)(ws + OFF_PART);

    k_prep    <<<dim3(2432), 256, 0, stream>>>(Wh, Wt, Wc, tf, pos, whT, wtT, wcg, ent);
    k_gemm_z  <<<dim3(8, 12, 2), 256, 0, stream>>>(ent, whT, wtT, bh, bt, zsp, zop);
    k_bilinear<<<dim3(8, RSPLIT), 256, 0, stream>>>(zsp, zop, wcg, ht, part);
    k_reduce  <<<dim3((L_ * (NPAIR / 4) + 255) / 256), 256, 0, stream>>>(part, bc, out);
}

// Round 7
// 222.651 us; speedup vs baseline: 1.5408x; 1.5408x over previous
//
#include <hip/hip_runtime.h>
#include <hip/hip_bf16.h>

typedef __bf16 bf16_t;
typedef bf16_t bf16x8 __attribute__((ext_vector_type(8)));
typedef float  f32x4  __attribute__((ext_vector_type(4)));

#define B_    16
#define S_    2048
#define H_    768
#define E_    32
#define M_    4
#define P_    128
#define L_    97
#define NPAIR 2048
#define RSPLIT 48

// workspace layout (bytes)
#define OFF_WHT  0u
#define OFF_WTT  (OFF_WHT + 768u*768u*2u)
#define OFF_WCG  (OFF_WTT + 768u*768u*2u)          // 768 chunks x (112 l x 64 j) halfs, XOR-swizzled
#define OFF_ENT  (OFF_WCG + 768u*14336u)
#define OFF_ZS   (OFF_ENT + 512u*768u*2u)
#define OFF_ZO   (OFF_ZS  + 512u*768u*2u)
#define OFF_PART (OFF_ZO  + 512u*768u*2u)          // 48 x 112 x 2048 bf16 split-K partials [c][l][n]

typedef __attribute__((address_space(1))) const unsigned gu32;
typedef __attribute__((address_space(3))) unsigned lu32;

static __device__ __forceinline__ float bf_lo(unsigned u) { return __builtin_bit_cast(float, u << 16); }
static __device__ __forceinline__ float bf_hi(unsigned u) { return __builtin_bit_cast(float, u & 0xffff0000u); }
static __device__ __forceinline__ unsigned short bf_bits(float f) {
    return __builtin_bit_cast(unsigned short, (bf16_t)f);
}

// ---------------- k_prep: fused transpose(Wh,Wt) + build WcG + entity sum ----------------
// blocks [0,1152): transpose; [1152,1920): wcg; [1920,2432): ent.
__global__ __launch_bounds__(256) void k_prep(const float* __restrict__ Wh,
                                              const float* __restrict__ Wt,
                                              const float* __restrict__ Wc,
                                              const float* __restrict__ tf,
                                              const int* __restrict__ pos,
                                              bf16_t* __restrict__ whT,
                                              bf16_t* __restrict__ wtT,
                                              unsigned* __restrict__ wcg,
                                              bf16_t* __restrict__ ent) {
    int bid = blockIdx.x;
    if (bid < 1152) {
        // ---- transpose Wh/Wt (768x768 f32) -> bf16 col-major ----
        __shared__ float tile[32][33];
        int z   = bid / 576;
        int rem = bid - z * 576;
        const float* W = z ? Wt : Wh;
        bf16_t* WT = z ? wtT : whT;
        int k0 = (rem % 24) * 32, c0 = (rem / 24) * 32;
        int tx = threadIdx.x & 31, ty = threadIdx.x >> 5;  // 32 x 8
        for (int r = 0; r < 4; r++) {
            int ky = ty + r * 8;
            tile[ky][tx] = W[(k0 + ky) * H_ + c0 + tx];
        }
        __syncthreads();
        for (int r = 0; r < 4; r++) {
            int cy = ty + r * 8;
            WT[(c0 + cy) * H_ + (k0 + tx)] = (bf16_t)tile[tx][cy];
        }
    } else if (bid < 1920) {
        // ---- build WcG bf16, chunk-major, XOR-swizzled within rows ----
        // Row l's 8 dword-groups stored at physical group g' = g ^ (l&7) so identity
        // global->LDS staging yields conflict-free b128 fragment reads in k_bilinear.
        int I = bid - 1152;                      // 0..767
        unsigned base_dw = (unsigned)I * 3584u;  // dwords per chunk = 112*32
        for (int r = 0; r < 14; r++) {
            int d  = threadIdx.x + 256 * r;      // dest dword in chunk 0..3583
            int l  = d >> 5;                     // 0..111
            int gp = (d >> 2) & 7;               // physical group
            int k  = d & 3;
            int gl = gp ^ (l & 7);               // logical group
            int j  = (gl * 4 + k) * 2;           // logical half index (even)
            int p  = I * 64 + j;                 // = kblk*4096 + i*64 + j
            float v0 = (l < L_) ? Wc[(size_t)p * L_ + l]       : 0.f;
            float v1 = (l < L_) ? Wc[(size_t)(p + 1) * L_ + l] : 0.f;
            unsigned pk = (unsigned)bf_bits(v0) | ((unsigned)bf_bits(v1) << 16);
            wcg[base_dw + d] = pk;
        }
    } else {
        // ---- entity features (dedup-weighted mention sum) -> bf16 ----
        int be = bid - 1920;    // b*32+e, 0..511
        int b  = be >> 5;
        int p0 = pos[be*4+0], p1 = pos[be*4+1], p2 = pos[be*4+2], p3 = pos[be*4+3];
        bool w1 = (p1 != p0);
        bool w2 = (p2 != p0) && (p2 != p1);
        bool w3 = (p3 != p0) && (p3 != p1) && (p3 != p2);
        const float* base = tf + (size_t)b * S_ * H_;
        for (int qq = 0; qq < 3; qq++) {
            int h = threadIdx.x + qq * 256;
            float s = base[(size_t)p0 * H_ + h];
            if (w1) s += base[(size_t)p1 * H_ + h];
            if (w2) s += base[(size_t)p2 * H_ + h];
            if (w3) s += base[(size_t)p3 * H_ + h];
            ent[(size_t)be * H_ + h] = (bf16_t)s;
        }
    }
}

// ---------------- K2: z_ent = tanh(ent @ W + b) via MFMA, per-entity (512 rows) ----------------
__global__ __launch_bounds__(256) void k_gemm_z(const bf16_t* __restrict__ ent,
                                                const bf16_t* __restrict__ whT,
                                                const bf16_t* __restrict__ wtT,
                                                const float* __restrict__ bh,
                                                const float* __restrict__ bt,
                                                bf16_t* __restrict__ zs,
                                                bf16_t* __restrict__ zo) {
    const bf16_t* WT  = blockIdx.z ? wtT : whT;
    const float* bias = blockIdx.z ? bt  : bh;
    bf16_t* outp      = blockIdx.z ? zo  : zs;
    int w = threadIdx.x >> 6, lane = threadIdx.x & 63;
    int ml = lane & 15, q = lane >> 4;
    int m0 = blockIdx.x * 64 + w * 16;   // entity row tile
    int c0 = blockIdx.y * 64;            // col tile base
    f32x4 zero4 = {0.f, 0.f, 0.f, 0.f};
    f32x4 acc[4] = {zero4, zero4, zero4, zero4};
    const bf16_t* aptr = ent + (size_t)(m0 + ml) * H_ + q * 8;
    for (int kk = 0; kk < 24; kk++) {
        bf16x8 a = *reinterpret_cast<const bf16x8*>(aptr + kk * 32);
        for (int lt = 0; lt < 4; lt++) {
            const bf16_t* bp = WT + (size_t)(c0 + lt * 16 + ml) * H_ + kk * 32 + q * 8;
            bf16x8 bfr = *reinterpret_cast<const bf16x8*>(bp);
            acc[lt] = __builtin_amdgcn_mfma_f32_16x16x32_bf16(a, bfr, acc[lt], 0, 0, 0);
        }
    }
    for (int lt = 0; lt < 4; lt++)
        for (int r = 0; r < 4; r++) {
            int row = q * 4 + r;
            int col = c0 + lt * 16 + ml;
            float v = tanhf(acc[lt][r] + bias[col]);
            outp[(size_t)(m0 + row) * H_ + col] = (bf16_t)v;
        }
}

// ---------------- K3: bilinear classifier, split-K, 4 waves x 4 n-tiles, dbuf async staging --
// logits[n,l] += zs[n,i] * ( sum_j zo[n,j] * Wc[kblk,i,j,l] ), inner sum via MFMA K=64.
// ht[] entity indices are BATCH-LOCAL (0..31); global entity = (n>>7)*32 + ht.
// LDS-BW-bound: every wave reads the full 14KB Wc slice per ii, so traffic ~ wave count.
// 4 waves x 4 n-tiles maximizes B-fragment reuse (4 n-tiles share each ds_read_b128).
// launch_bounds(256,2): DO NOT raise to 3 — R6 measured: the VGPR cap (170) forces the
// compiler to 84 VGPRs, spilling acc[4][7] to scratch (FETCH 80MB/WRITE 380MB, 13->160us).
// Live state ~150 VGPR: 2 blocks/CU is this kernel's occupancy ceiling.
__global__ __launch_bounds__(256, 2) void k_bilinear(const bf16_t* __restrict__ zs,
                                                     const bf16_t* __restrict__ zo,
                                                     const unsigned* __restrict__ wcg,
                                                     const int* __restrict__ ht,
                                                     unsigned* __restrict__ pout) {
    __shared__ __align__(16) unsigned wc_lds[2][112 * 32];  // dbuf, 14336 B each, swizzled
    __shared__ unsigned short zs_lds[16 * 256];             // [i][pair-in-block]
    int nb = blockIdx.x;           // 0..7  (256 pairs each)
    int c  = blockIdx.y;           // 0..47 (16 I's each)
    int I0 = c * 16;
    int kblk = I0 >> 6;
    int i0   = I0 & 63;
    int t = threadIdx.x;
    int w = t >> 6, lane = t & 63, ml = lane & 15, q = lane >> 4;
    int nbase = nb * 256;

    // stage zs transposed: zs_lds[ii][p] = zs_ent[global_ent(ht[n,0])][kblk*64 + i0 + ii]
    {
        int n  = nbase + t;
        int es = (n >> 7) * E_ + ht[n * 2 + 0];
        const unsigned short* src =
            reinterpret_cast<const unsigned short*>(zs) + (size_t)es * H_ + kblk * 64 + i0;
        uint4 u0 = *reinterpret_cast<const uint4*>(src);
        uint4 u1 = *reinterpret_cast<const uint4*>(src + 8);
        unsigned vals[8] = {u0.x, u0.y, u0.z, u0.w, u1.x, u1.y, u1.z, u1.w};
        for (int d = 0; d < 8; d++) {
            zs_lds[(2 * d) * 256 + t]     = (unsigned short)(vals[d] & 0xffffu);
            zs_lds[(2 * d + 1) * 256 + t] = (unsigned short)(vals[d] >> 16);
        }
    }

    // zo A-operand fragments: wave w owns n-tiles (w*4+nt)
    bf16x8 zoA[4][2];
    for (int nt = 0; nt < 4; nt++) {
        int n  = nbase + (w * 4 + nt) * 16 + ml;
        int eo = (n >> 7) * E_ + ht[n * 2 + 1];
        const bf16_t* src = zo + (size_t)eo * H_ + kblk * 64;
        zoA[nt][0] = *reinterpret_cast<const bf16x8*>(src + 0 * 32 + q * 8);
        zoA[nt][1] = *reinterpret_cast<const bf16x8*>(src + 1 * 32 + q * 8);
    }

    f32x4 zero4 = {0.f, 0.f, 0.f, 0.f};
    f32x4 acc[4][7];
    for (int nt = 0; nt < 4; nt++)
        for (int lt = 0; lt < 7; lt++) acc[nt][lt] = zero4;

    const unsigned* gsrc = wcg + (size_t)I0 * 3584u;

    // async prefetch chunk 0 into buf 0 (identity copy; swizzle pre-baked in wcg)
    for (int pp = w; pp < 14; pp += 4)
        __builtin_amdgcn_global_load_lds((gu32*)(gsrc + pp * 256 + lane * 4),
                                         (lu32*)&wc_lds[0][pp * 256], 16, 0, 0);
    __syncthreads();  // zs_lds ready + prefetch(0) drained

    int sw = ml & 7;  // l&7 == ml&7 for l = lt*16+ml
    for (int ii = 0; ii < 16; ii++) {
        int pb = ii & 1;
        // issue prefetch of chunk ii+1 BEFORE compute so latency hides behind MFMA
        if (ii < 15) {
            const unsigned* g2 = gsrc + (size_t)(ii + 1) * 3584u;
            for (int pp = w; pp < 14; pp += 4)
                __builtin_amdgcn_global_load_lds((gu32*)(g2 + pp * 256 + lane * 4),
                                                 (lu32*)&wc_lds[1 - pb][pp * 256], 16, 0, 0);
        }

        // zs scalars for this i: rows q*4+r of each n-tile
        float zsv[4][4];
        for (int nt = 0; nt < 4; nt++) {
            const unsigned* zp = reinterpret_cast<const unsigned*>(
                &zs_lds[ii * 256 + (w * 4 + nt) * 16 + q * 4]);
            unsigned z0 = zp[0], z1 = zp[1];
            zsv[nt][0] = bf_lo(z0); zsv[nt][1] = bf_hi(z0);
            zsv[nt][2] = bf_lo(z1); zsv[nt][3] = bf_hi(z1);
        }

        const unsigned short* wch = reinterpret_cast<const unsigned short*>(wc_lds[pb]);
        for (int lt = 0; lt < 7; lt++) {
            int l = lt * 16 + ml;
            bf16x8 b0 = *reinterpret_cast<const bf16x8*>(wch + l * 64 + ((q ^ sw) * 8));
            bf16x8 b1 = *reinterpret_cast<const bf16x8*>(wch + l * 64 + (((4 + q) ^ sw) * 8));
            for (int nt = 0; nt < 4; nt++) {
                f32x4 dres = __builtin_amdgcn_mfma_f32_16x16x32_bf16(zoA[nt][0], b0, zero4, 0, 0, 0);
                dres = __builtin_amdgcn_mfma_f32_16x16x32_bf16(zoA[nt][1], b1, dres, 0, 0, 0);
                for (int r = 0; r < 4; r++) acc[nt][lt][r] += zsv[nt][r] * dres[r];
            }
        }
        __syncthreads();  // drains prefetch(ii+1); all waves done with buf pb
    }

    // epilogue: bf16 partials, layout part[c][l][n] — lane's 4 values are consecutive n
    // for one l, so pack into one 8B store.
    for (int nt = 0; nt < 4; nt++) {
        int n0 = nbase + (w * 4 + nt) * 16 + q * 4;
        for (int lt = 0; lt < 7; lt++) {
            int l = lt * 16 + ml;
            unsigned d0 = (unsigned)bf_bits(acc[nt][lt][0]) | ((unsigned)bf_bits(acc[nt][lt][1]) << 16);
            unsigned d1 = (unsigned)bf_bits(acc[nt][lt][2]) | ((unsigned)bf_bits(acc[nt][lt][3]) << 16);
            uint2 pk = {d0, d1};
            *reinterpret_cast<uint2*>(pout + (((size_t)c * 112 + l) * NPAIR + n0) / 2) = pk;
        }
    }
}

// ---------------- K4: split-K reduction + bias (bf16 partials, [c][l][n]) ----------------
__global__ __launch_bounds__(256) void k_reduce(const unsigned* __restrict__ part,
                                                const float* __restrict__ bc,
                                                float* __restrict__ out) {
    int t = blockIdx.x * 256 + threadIdx.x;   // over 97 * 512
    if (t >= L_ * (NPAIR / 4)) return;
    int n4 = t & 511;            // n/4
    int l  = t >> 9;             // 0..96
    const unsigned* p = part + (size_t)l * (NPAIR / 2) + n4 * 2;
    f32x4 s = {0.f, 0.f, 0.f, 0.f};
    #pragma unroll
    for (int cc = 0; cc < RSPLIT; cc++) {
        uint2 v = *reinterpret_cast<const uint2*>(p + (size_t)cc * 112 * (NPAIR / 2));
        s[0] += bf_lo(v.x); s[1] += bf_hi(v.x);
        s[2] += bf_lo(v.y); s[3] += bf_hi(v.y);
    }
    float b = bc[l];
    #pragma unroll
    for (int e = 0; e < 4; e++)
        out[(size_t)(n4 * 4 + e) * L_ + l] = s[e] + b;
}

extern "C" void kernel_launch(void* const* d_in, const int* in_sizes, int n_in,
                              void* d_out, int out_size, void* d_ws, size_t ws_size,
                              hipStream_t stream) {
    (void)in_sizes; (void)n_in; (void)out_size; (void)ws_size;
    const float* tf  = (const float*)d_in[0];
    const int*   pos = (const int*)d_in[1];
    const int*   ht  = (const int*)d_in[2];
    const float* Wh  = (const float*)d_in[3];
    const float* bh  = (const float*)d_in[4];
    const float* Wt  = (const float*)d_in[5];
    const float* bt  = (const float*)d_in[6];
    const float* Wc  = (const float*)d_in[7];
    const float* bc  = (const float*)d_in[8];
    float* out = (float*)d_out;
    char*  ws  = (char*)d_ws;

    bf16_t*   whT  = (bf16_t*)(ws + OFF_WHT);
    bf16_t*   wtT  = (bf16_t*)(ws + OFF_WTT);
    unsigned* wcg  = (unsigned*)(ws + OFF_WCG);
    bf16_t*   ent  = (bf16_t*)(ws + OFF_ENT);
    bf16_t*   zsp  = (bf16_t*)(ws + OFF_ZS);
    bf16_t*   zop  = (bf16_t*)(ws + OFF_ZO);
    unsigned* part = (unsigned*)(ws + OFF_PART);

    k_prep    <<<dim3(2432), 256, 0, stream>>>(Wh, Wt, Wc, tf, pos, whT, wtT, wcg, ent);
    k_gemm_z  <<<dim3(8, 12, 2), 256, 0, stream>>>(ent, whT, wtT, bh, bt, zsp, zop);
    k_bilinear<<<dim3(8, RSPLIT), 256, 0, stream>>>(zsp, zop, wcg, ht, part);
    k_reduce  <<<dim3((L_ * (NPAIR / 4) + 255) / 256), 256, 0, stream>>>(part, bc, out);
}

// Round 8
// 217.996 us; speedup vs baseline: 1.5737x; 1.0214x over previous
//
#include <hip/hip_runtime.h>
#include <hip/hip_bf16.h>

typedef __bf16 bf16_t;
typedef bf16_t bf16x8 __attribute__((ext_vector_type(8)));
typedef float  f32x4  __attribute__((ext_vector_type(4)));

#define B_    16
#define S_    2048
#define H_    768
#define E_    32
#define M_    4
#define P_    128
#define L_    97
#define NPAIR 2048
#define RSPLIT 48

// workspace layout (bytes)
#define OFF_WHT  0u
#define OFF_WTT  (OFF_WHT + 768u*768u*2u)
#define OFF_WCG  (OFF_WTT + 768u*768u*2u)          // 768 chunks x (112 l x 64 j) halfs, XOR-swizzled
#define OFF_ENT  (OFF_WCG + 768u*14336u)
#define OFF_ZS   (OFF_ENT + 512u*768u*2u)
#define OFF_ZO   (OFF_ZS  + 512u*768u*2u)
#define OFF_PART (OFF_ZO  + 512u*768u*2u)          // 48 x 112 x 2048 bf16 split-K partials [c][l][n]

typedef __attribute__((address_space(1))) const unsigned gu32;
typedef __attribute__((address_space(3))) unsigned lu32;

static __device__ __forceinline__ float bf_lo(unsigned u) { return __builtin_bit_cast(float, u << 16); }
static __device__ __forceinline__ float bf_hi(unsigned u) { return __builtin_bit_cast(float, u & 0xffff0000u); }
static __device__ __forceinline__ unsigned short bf_bits(float f) {
    return __builtin_bit_cast(unsigned short, (bf16_t)f);
}

// ---------------- k_prep: fused transpose(Wh,Wt) + build WcG + entity sum ----------------
// blocks [0,1152): transpose; [1152,1920): wcg; [1920,2432): ent.
__global__ __launch_bounds__(256) void k_prep(const float* __restrict__ Wh,
                                              const float* __restrict__ Wt,
                                              const float* __restrict__ Wc,
                                              const float* __restrict__ tf,
                                              const int* __restrict__ pos,
                                              bf16_t* __restrict__ whT,
                                              bf16_t* __restrict__ wtT,
                                              unsigned* __restrict__ wcg,
                                              bf16_t* __restrict__ ent) {
    int bid = blockIdx.x;
    if (bid < 1152) {
        // ---- transpose Wh/Wt (768x768 f32) -> bf16 col-major ----
        __shared__ float tile[32][33];
        int z   = bid / 576;
        int rem = bid - z * 576;
        const float* W = z ? Wt : Wh;
        bf16_t* WT = z ? wtT : whT;
        int k0 = (rem % 24) * 32, c0 = (rem / 24) * 32;
        int tx = threadIdx.x & 31, ty = threadIdx.x >> 5;  // 32 x 8
        for (int r = 0; r < 4; r++) {
            int ky = ty + r * 8;
            tile[ky][tx] = W[(k0 + ky) * H_ + c0 + tx];
        }
        __syncthreads();
        for (int r = 0; r < 4; r++) {
            int cy = ty + r * 8;
            WT[(c0 + cy) * H_ + (k0 + tx)] = (bf16_t)tile[tx][cy];
        }
    } else if (bid < 1920) {
        // ---- build WcG bf16, chunk-major, XOR-swizzled within rows ----
        // Chunk I's source slab Wc[I*64 .. I*64+63][0..96] is CONTIGUOUS (64x97 floats):
        // Phase A stages it into LDS with fully-coalesced linear reads (the old direct
        // path read stride-776B per lane: 64 cachelines per wave-load, ~16x transaction
        // overfetch at L2/TA). Phase B packs bf16 pairs with the XOR swizzle
        // (g' = g ^ (l&7)) so identity global->LDS staging in k_bilinear yields
        // conflict-free b128 fragment reads. Output bits identical to the old path.
        __shared__ float ldsw[64 * 98];          // row pad 97->98: phase-A addr = idx+p, conflict-free
        int I = bid - 1152;                      // 0..767
        const float* src = Wc + (size_t)I * 64 * L_;
        for (int it = 0; it < 25; it++) {
            int idx = it * 256 + threadIdx.x;    // 0..6399, slab has 6208
            if (idx < 64 * L_) {
                int p = idx / L_;                // local j, 0..63
                int l = idx - p * L_;
                ldsw[p * 98 + l] = src[idx];
            }
        }
        __syncthreads();
        unsigned base_dw = (unsigned)I * 3584u;  // dwords per chunk = 112*32
        for (int r = 0; r < 14; r++) {
            int d  = threadIdx.x + 256 * r;      // dest dword in chunk 0..3583
            int l  = d >> 5;                     // 0..111
            int gp = (d >> 2) & 7;               // physical group
            int k  = d & 3;
            int gl = gp ^ (l & 7);               // logical group
            int j  = (gl * 4 + k) * 2;           // logical half index (even)
            float v0 = (l < L_) ? ldsw[j * 98 + l]       : 0.f;  // = Wc[(I*64+j)*L + l]
            float v1 = (l < L_) ? ldsw[(j + 1) * 98 + l] : 0.f;
            unsigned pk = (unsigned)bf_bits(v0) | ((unsigned)bf_bits(v1) << 16);
            wcg[base_dw + d] = pk;
        }
    } else {
        // ---- entity features (dedup-weighted mention sum) -> bf16 ----
        int be = bid - 1920;    // b*32+e, 0..511
        int b  = be >> 5;
        int p0 = pos[be*4+0], p1 = pos[be*4+1], p2 = pos[be*4+2], p3 = pos[be*4+3];
        bool w1 = (p1 != p0);
        bool w2 = (p2 != p0) && (p2 != p1);
        bool w3 = (p3 != p0) && (p3 != p1) && (p3 != p2);
        const float* base = tf + (size_t)b * S_ * H_;
        for (int qq = 0; qq < 3; qq++) {
            int h = threadIdx.x + qq * 256;
            float s = base[(size_t)p0 * H_ + h];
            if (w1) s += base[(size_t)p1 * H_ + h];
            if (w2) s += base[(size_t)p2 * H_ + h];
            if (w3) s += base[(size_t)p3 * H_ + h];
            ent[(size_t)be * H_ + h] = (bf16_t)s;
        }
    }
}

// ---------------- K2: z_ent = tanh(ent @ W + b) via MFMA, per-entity (512 rows) ----------------
__global__ __launch_bounds__(256) void k_gemm_z(const bf16_t* __restrict__ ent,
                                                const bf16_t* __restrict__ whT,
                                                const bf16_t* __restrict__ wtT,
                                                const float* __restrict__ bh,
                                                const float* __restrict__ bt,
                                                bf16_t* __restrict__ zs,
                                                bf16_t* __restrict__ zo) {
    const bf16_t* WT  = blockIdx.z ? wtT : whT;
    const float* bias = blockIdx.z ? bt  : bh;
    bf16_t* outp      = blockIdx.z ? zo  : zs;
    int w = threadIdx.x >> 6, lane = threadIdx.x & 63;
    int ml = lane & 15, q = lane >> 4;
    int m0 = blockIdx.x * 64 + w * 16;   // entity row tile
    int c0 = blockIdx.y * 64;            // col tile base
    f32x4 zero4 = {0.f, 0.f, 0.f, 0.f};
    f32x4 acc[4] = {zero4, zero4, zero4, zero4};
    const bf16_t* aptr = ent + (size_t)(m0 + ml) * H_ + q * 8;
    for (int kk = 0; kk < 24; kk++) {
        bf16x8 a = *reinterpret_cast<const bf16x8*>(aptr + kk * 32);
        for (int lt = 0; lt < 4; lt++) {
            const bf16_t* bp = WT + (size_t)(c0 + lt * 16 + ml) * H_ + kk * 32 + q * 8;
            bf16x8 bfr = *reinterpret_cast<const bf16x8*>(bp);
            acc[lt] = __builtin_amdgcn_mfma_f32_16x16x32_bf16(a, bfr, acc[lt], 0, 0, 0);
        }
    }
    for (int lt = 0; lt < 4; lt++)
        for (int r = 0; r < 4; r++) {
            int row = q * 4 + r;
            int col = c0 + lt * 16 + ml;
            float v = tanhf(acc[lt][r] + bias[col]);
            outp[(size_t)(m0 + row) * H_ + col] = (bf16_t)v;
        }
}

// ---------------- K3: bilinear classifier, split-K, 4 waves x 4 n-tiles, dbuf async staging --
// logits[n,l] += zs[n,i] * ( sum_j zo[n,j] * Wc[kblk,i,j,l] ), inner sum via MFMA K=64.
// ht[] entity indices are BATCH-LOCAL (0..31); global entity = (n>>7)*32 + ht.
// LDS-BW-bound: every wave reads the full 14KB Wc slice per ii, so traffic ~ wave count.
// 4 waves x 4 n-tiles maximizes B-fragment reuse (4 n-tiles share each ds_read_b128).
// launch_bounds(256,2): DO NOT raise to 3 — R6 measured: the VGPR cap (170) forces the
// compiler to 84 VGPRs, spilling acc[4][7] to scratch (FETCH 80MB/WRITE 380MB, 13->160us).
// Live state ~150 VGPR: 2 blocks/CU is this kernel's occupancy ceiling.
__global__ __launch_bounds__(256, 2) void k_bilinear(const bf16_t* __restrict__ zs,
                                                     const bf16_t* __restrict__ zo,
                                                     const unsigned* __restrict__ wcg,
                                                     const int* __restrict__ ht,
                                                     unsigned* __restrict__ pout) {
    __shared__ __align__(16) unsigned wc_lds[2][112 * 32];  // dbuf, 14336 B each, swizzled
    __shared__ unsigned short zs_lds[16 * 256];             // [i][pair-in-block]
    int nb = blockIdx.x;           // 0..7  (256 pairs each)
    int c  = blockIdx.y;           // 0..47 (16 I's each)
    int I0 = c * 16;
    int kblk = I0 >> 6;
    int i0   = I0 & 63;
    int t = threadIdx.x;
    int w = t >> 6, lane = t & 63, ml = lane & 15, q = lane >> 4;
    int nbase = nb * 256;

    // stage zs transposed: zs_lds[ii][p] = zs_ent[global_ent(ht[n,0])][kblk*64 + i0 + ii]
    {
        int n  = nbase + t;
        int es = (n >> 7) * E_ + ht[n * 2 + 0];
        const unsigned short* src =
            reinterpret_cast<const unsigned short*>(zs) + (size_t)es * H_ + kblk * 64 + i0;
        uint4 u0 = *reinterpret_cast<const uint4*>(src);
        uint4 u1 = *reinterpret_cast<const uint4*>(src + 8);
        unsigned vals[8] = {u0.x, u0.y, u0.z, u0.w, u1.x, u1.y, u1.z, u1.w};
        for (int d = 0; d < 8; d++) {
            zs_lds[(2 * d) * 256 + t]     = (unsigned short)(vals[d] & 0xffffu);
            zs_lds[(2 * d + 1) * 256 + t] = (unsigned short)(vals[d] >> 16);
        }
    }

    // zo A-operand fragments: wave w owns n-tiles (w*4+nt)
    bf16x8 zoA[4][2];
    for (int nt = 0; nt < 4; nt++) {
        int n  = nbase + (w * 4 + nt) * 16 + ml;
        int eo = (n >> 7) * E_ + ht[n * 2 + 1];
        const bf16_t* src = zo + (size_t)eo * H_ + kblk * 64;
        zoA[nt][0] = *reinterpret_cast<const bf16x8*>(src + 0 * 32 + q * 8);
        zoA[nt][1] = *reinterpret_cast<const bf16x8*>(src + 1 * 32 + q * 8);
    }

    f32x4 zero4 = {0.f, 0.f, 0.f, 0.f};
    f32x4 acc[4][7];
    for (int nt = 0; nt < 4; nt++)
        for (int lt = 0; lt < 7; lt++) acc[nt][lt] = zero4;

    const unsigned* gsrc = wcg + (size_t)I0 * 3584u;

    // async prefetch chunk 0 into buf 0 (identity copy; swizzle pre-baked in wcg)
    for (int pp = w; pp < 14; pp += 4)
        __builtin_amdgcn_global_load_lds((gu32*)(gsrc + pp * 256 + lane * 4),
                                         (lu32*)&wc_lds[0][pp * 256], 16, 0, 0);
    __syncthreads();  // zs_lds ready + prefetch(0) drained

    int sw = ml & 7;  // l&7 == ml&7 for l = lt*16+ml
    for (int ii = 0; ii < 16; ii++) {
        int pb = ii & 1;
        // issue prefetch of chunk ii+1 BEFORE compute so latency hides behind MFMA
        if (ii < 15) {
            const unsigned* g2 = gsrc + (size_t)(ii + 1) * 3584u;
            for (int pp = w; pp < 14; pp += 4)
                __builtin_amdgcn_global_load_lds((gu32*)(g2 + pp * 256 + lane * 4),
                                                 (lu32*)&wc_lds[1 - pb][pp * 256], 16, 0, 0);
        }

        // zs scalars for this i: rows q*4+r of each n-tile
        float zsv[4][4];
        for (int nt = 0; nt < 4; nt++) {
            const unsigned* zp = reinterpret_cast<const unsigned*>(
                &zs_lds[ii * 256 + (w * 4 + nt) * 16 + q * 4]);
            unsigned z0 = zp[0], z1 = zp[1];
            zsv[nt][0] = bf_lo(z0); zsv[nt][1] = bf_hi(z0);
            zsv[nt][2] = bf_lo(z1); zsv[nt][3] = bf_hi(z1);
        }

        const unsigned short* wch = reinterpret_cast<const unsigned short*>(wc_lds[pb]);
        for (int lt = 0; lt < 7; lt++) {
            int l = lt * 16 + ml;
            bf16x8 b0 = *reinterpret_cast<const bf16x8*>(wch + l * 64 + ((q ^ sw) * 8));
            bf16x8 b1 = *reinterpret_cast<const bf16x8*>(wch + l * 64 + (((4 + q) ^ sw) * 8));
            for (int nt = 0; nt < 4; nt++) {
                f32x4 dres = __builtin_amdgcn_mfma_f32_16x16x32_bf16(zoA[nt][0], b0, zero4, 0, 0, 0);
                dres = __builtin_amdgcn_mfma_f32_16x16x32_bf16(zoA[nt][1], b1, dres, 0, 0, 0);
                for (int r = 0; r < 4; r++) acc[nt][lt][r] += zsv[nt][r] * dres[r];
            }
        }
        __syncthreads();  // drains prefetch(ii+1); all waves done with buf pb
    }

    // epilogue: bf16 partials, layout part[c][l][n] — lane's 4 values are consecutive n
    // for one l, so pack into one 8B store.
    for (int nt = 0; nt < 4; nt++) {
        int n0 = nbase + (w * 4 + nt) * 16 + q * 4;
        for (int lt = 0; lt < 7; lt++) {
            int l = lt * 16 + ml;
            unsigned d0 = (unsigned)bf_bits(acc[nt][lt][0]) | ((unsigned)bf_bits(acc[nt][lt][1]) << 16);
            unsigned d1 = (unsigned)bf_bits(acc[nt][lt][2]) | ((unsigned)bf_bits(acc[nt][lt][3]) << 16);
            uint2 pk = {d0, d1};
            *reinterpret_cast<uint2*>(pout + (((size_t)c * 112 + l) * NPAIR + n0) / 2) = pk;
        }
    }
}

// ---------------- K4: split-K reduction + bias (bf16 partials, [c][l][n]) ----------------
__global__ __launch_bounds__(256) void k_reduce(const unsigned* __restrict__ part,
                                                const float* __restrict__ bc,
                                                float* __restrict__ out) {
    int t = blockIdx.x * 256 + threadIdx.x;   // over 97 * 512
    if (t >= L_ * (NPAIR / 4)) return;
    int n4 = t & 511;            // n/4
    int l  = t >> 9;             // 0..96
    const unsigned* p = part + (size_t)l * (NPAIR / 2) + n4 * 2;
    f32x4 s = {0.f, 0.f, 0.f, 0.f};
    #pragma unroll
    for (int cc = 0; cc < RSPLIT; cc++) {
        uint2 v = *reinterpret_cast<const uint2*>(p + (size_t)cc * 112 * (NPAIR / 2));
        s[0] += bf_lo(v.x); s[1] += bf_hi(v.x);
        s[2] += bf_lo(v.y); s[3] += bf_hi(v.y);
    }
    float b = bc[l];
    #pragma unroll
    for (int e = 0; e < 4; e++)
        out[(size_t)(n4 * 4 + e) * L_ + l] = s[e] + b;
}

extern "C" void kernel_launch(void* const* d_in, const int* in_sizes, int n_in,
                              void* d_out, int out_size, void* d_ws, size_t ws_size,
                              hipStream_t stream) {
    (void)in_sizes; (void)n_in; (void)out_size; (void)ws_size;
    const float* tf  = (const float*)d_in[0];
    const int*   pos = (const int*)d_in[1];
    const int*   ht  = (const int*)d_in[2];
    const float* Wh  = (const float*)d_in[3];
    const float* bh  = (const float*)d_in[4];
    const float* Wt  = (const float*)d_in[5];
    const float* bt  = (const float*)d_in[6];
    const float* Wc  = (const float*)d_in[7];
    const float* bc  = (const float*)d_in[8];
    float* out = (float*)d_out;
    char*  ws  = (char*)d_ws;

    bf16_t*   whT  = (bf16_t*)(ws + OFF_WHT);
    bf16_t*   wtT  = (bf16_t*)(ws + OFF_WTT);
    unsigned* wcg  = (unsigned*)(ws + OFF_WCG);
    bf16_t*   ent  = (bf16_t*)(ws + OFF_ENT);
    bf16_t*   zsp  = (bf16_t*)(ws + OFF_ZS);
    bf16_t*   zop  = (bf16_t*)(ws + OFF_ZO);
    unsigned* part = (unsigned*)(ws + OFF_PART);

    k_prep    <<<dim3(2432), 256, 0, stream>>>(Wh, Wt, Wc, tf, pos, whT, wtT, wcg, ent);
    k_gemm_z  <<<dim3(8, 12, 2), 256, 0, stream>>>(ent, whT, wtT, bh, bt, zsp, zop);
    k_bilinear<<<dim3(8, RSPLIT), 256, 0, stream>>>(zsp, zop, wcg, ht, part);
    k_reduce  <<<dim3((L_ * (NPAIR / 4) + 255) / 256), 256, 0, stream>>>(part, bc, out);
}